// Round 1
// baseline (572.130 us; speedup 1.0000x reference)
//
#include <hip/hip_runtime.h>
#include <hip/hip_bf16.h>
#include <math.h>

#define NB 400
#define CCH 64

// ---------------------------------------------------------------------------
// K1: Tt[b][j][i] = relu(tanh(max_c R[b,c,i,j]))   (transposed store)
// One block per (b, 64x64 tile of (i,j)). 256 threads; each owns a 4x4 patch.
// Reads R coalesced (float4 along j), transposes through LDS, writes Tt
// coalesced (float4 along i).
// ---------------------------------------------------------------------------
__global__ __launch_bounds__(256) void k1_max_tanh_T(
    const float* __restrict__ R, float* __restrict__ Tt) {
  const int b  = blockIdx.z;
  const int i0 = blockIdx.y * 64;
  const int j0 = blockIdx.x * 64;
  const int tid = threadIdx.x;
  const int tj = tid & 15;    // j-group: 4 floats each
  const int ti = tid >> 4;    // i-group: 4 rows each
  const int jbase = j0 + tj * 4;
  const int ibase = i0 + ti * 4;

  float m[4][4];
#pragma unroll
  for (int a = 0; a < 4; ++a)
#pragma unroll
    for (int d = 0; d < 4; ++d) m[a][d] = -INFINITY;

  const float* Rb = R + (size_t)b * CCH * NB * NB;
  const bool jok = (jbase < NB);  // 400 % 4 == 0, so whole group valid or not

  for (int c = 0; c < CCH; ++c) {
    const float* Rc = Rb + (size_t)c * NB * NB;
#pragma unroll
    for (int a = 0; a < 4; ++a) {
      const int i = ibase + a;
      if (jok && i < NB) {
        float4 v = *reinterpret_cast<const float4*>(Rc + (size_t)i * NB + jbase);
        m[a][0] = fmaxf(m[a][0], v.x);
        m[a][1] = fmaxf(m[a][1], v.y);
        m[a][2] = fmaxf(m[a][2], v.z);
        m[a][3] = fmaxf(m[a][3], v.w);
      }
    }
  }

  // tile[j_local][i_local], +4 pad keeps float4 alignment & breaks conflicts
  __shared__ float tile[64][68];
#pragma unroll
  for (int a = 0; a < 4; ++a) {
#pragma unroll
    for (int d = 0; d < 4; ++d) {
      float t = tanhf(m[a][d]);
      t = fmaxf(t, 0.0f);
      tile[tj * 4 + d][ti * 4 + a] = t;
    }
  }
  __syncthreads();

  // write out transposed: Tt[b][jg][ig], threads contiguous along i
  const int wi = tid & 15;   // i-group (float4)
  const int wj = tid >> 4;   // j rows, 4 per thread
#pragma unroll
  for (int r = 0; r < 4; ++r) {
    const int jl = wj * 4 + r;
    const int jg = j0 + jl;
    const int ig = i0 + wi * 4;
    if (jg < NB && ig < NB) {
      float4 v;
      v.x = tile[jl][wi * 4 + 0];
      v.y = tile[jl][wi * 4 + 1];
      v.z = tile[jl][wi * 4 + 2];
      v.w = tile[jl][wi * 4 + 3];
      *reinterpret_cast<float4*>(Tt + ((size_t)b * NB + jg) * NB + ig) = v;
    }
  }
}

// ---------------------------------------------------------------------------
// K2: x[b][c][k] = sum_n R[b,c,n,k] * Tt[b][n][k]
// One block per (b,c). 256 threads = 2 n-halves x 100 active float4 k-groups.
// Pure streaming multiply-reduce; both operands coalesced.
// ---------------------------------------------------------------------------
__global__ __launch_bounds__(256) void k2_reduce_n(
    const float* __restrict__ R, const float* __restrict__ Tt,
    float* __restrict__ x) {
  const int c = blockIdx.x;
  const int b = blockIdx.y;
  const int tid = threadIdx.x;
  const int half = tid >> 7;   // 0 or 1
  const int k4 = tid & 127;    // active if < 100
  const int kk = k4 * 4;

  const float* Rbc = R + ((size_t)b * CCH + c) * NB * NB;
  const float* Ttb = Tt + (size_t)b * NB * NB;

  float4 acc = make_float4(0.f, 0.f, 0.f, 0.f);
  if (k4 < 100) {
    const int n0 = half * 200;
#pragma unroll 4
    for (int n = n0; n < n0 + 200; ++n) {
      float4 r = *reinterpret_cast<const float4*>(Rbc + (size_t)n * NB + kk);
      float4 t = *reinterpret_cast<const float4*>(Ttb + (size_t)n * NB + kk);
      acc.x += r.x * t.x;
      acc.y += r.y * t.y;
      acc.z += r.z * t.z;
      acc.w += r.w * t.w;
    }
  }

  __shared__ float4 red[128];
  if (half == 1 && k4 < 100) red[k4] = acc;
  __syncthreads();
  if (half == 0 && k4 < 100) {
    float4 o = red[k4];
    acc.x += o.x; acc.y += o.y; acc.z += o.z; acc.w += o.w;
    *reinterpret_cast<float4*>(x + ((size_t)b * CCH + c) * NB + kk) = acc;
  }
}

// ---------------------------------------------------------------------------
// K3: out[b][o][n] = bias[o] + sum_c W[o][c] * x[b][c][n]
// Block per (b, 64-wide n tile). W staged in LDS transposed to [c][o] so each
// LDS read is wave-uniform (broadcast). Each thread: 1 n, 16 o's.
// ---------------------------------------------------------------------------
__global__ __launch_bounds__(256) void k3_linear(
    const float* __restrict__ x, const float* __restrict__ W,
    const float* __restrict__ bias, float* __restrict__ out) {
  const int b  = blockIdx.y;
  const int n0 = blockIdx.x * 64;
  const int tid = threadIdx.x;
  const int nl = tid & 63;
  const int og = tid >> 6;       // wave id 0..3
  const int o0 = og * 16;
  const int n = n0 + nl;

  __shared__ float Ws[64][64];   // Ws[c][o] = W[o][c]
  for (int idx = tid; idx < 64 * 64; idx += 256) {
    const int o = idx >> 6, c = idx & 63;
    Ws[c][o] = W[idx];
  }
  __syncthreads();

  float acc[16];
#pragma unroll
  for (int t = 0; t < 16; ++t) acc[t] = bias[o0 + t];

  if (n < NB) {
    const float* xb = x + (size_t)b * CCH * NB;
    for (int cc = 0; cc < CCH; ++cc) {
      const float xv = xb[(size_t)cc * NB + n];
#pragma unroll
      for (int q = 0; q < 4; ++q) {
        float4 w = *reinterpret_cast<const float4*>(&Ws[cc][o0 + q * 4]);
        acc[q * 4 + 0] += w.x * xv;
        acc[q * 4 + 1] += w.y * xv;
        acc[q * 4 + 2] += w.z * xv;
        acc[q * 4 + 3] += w.w * xv;
      }
    }
#pragma unroll
    for (int t = 0; t < 16; ++t) {
      out[((size_t)b * CCH + (o0 + t)) * NB + n] = acc[t];
    }
  }
}

// ---------------------------------------------------------------------------
extern "C" void kernel_launch(void* const* d_in, const int* in_sizes, int n_in,
                              void* d_out, int out_size, void* d_ws, size_t ws_size,
                              hipStream_t stream) {
  const float* R    = (const float*)d_in[0];   // (8,64,400,400)
  const float* W    = (const float*)d_in[1];   // (64,64)
  const float* bias = (const float*)d_in[2];   // (64,)
  float* out = (float*)d_out;                  // (8,64,400,1)

  float* Tt = (float*)d_ws;                    // 8*400*400 = 1,280,000 floats
  float* x  = (float*)d_ws + (size_t)8 * NB * NB;  // 8*64*400 = 204,800 floats

  dim3 g1((NB + 63) / 64, (NB + 63) / 64, 8);  // 7 x 7 x 8
  k1_max_tanh_T<<<g1, 256, 0, stream>>>(R, Tt);

  dim3 g2(CCH, 8);                             // 64 x 8
  k2_reduce_n<<<g2, 256, 0, stream>>>(R, Tt, x);

  dim3 g3((NB + 63) / 64, 8);                  // 7 x 8
  k3_linear<<<g3, 256, 0, stream>>>(x, W, bias, out);
}

// Round 2
// 507.336 us; speedup vs baseline: 1.1277x; 1.1277x over previous
//
#include <hip/hip_runtime.h>
#include <hip/hip_bf16.h>
#include <math.h>

#define NB 400
#define CCH 64
#define IMG ((size_t)NB * NB)   // 160000

// ---------------------------------------------------------------------------
// K1: Tt[b][j][i] = relu(tanh(max_c R[b,c,i,j]))   (transposed store)
// Block = (b, 4-row strip). 512 threads: irow = tid>>7 (0..3), k4 = tid&127
// (active < 100, each owns a float4 along j). Full-row 1600B coalesced reads.
// Grid 100x8 = 800 blocks x 8 waves -> ~12.5 waves/SIMD.
// ---------------------------------------------------------------------------
__global__ __launch_bounds__(512) void k1_max_tanh_T(
    const float* __restrict__ R, float* __restrict__ Tt) {
  const int b    = blockIdx.y;
  const int i0   = blockIdx.x * 4;       // 100 strips of 4 rows
  const int tid  = threadIdx.x;
  const int irow = tid >> 7;             // 0..3
  const int k4   = tid & 127;            // float4 group, active if < 100

  float4 m = make_float4(-INFINITY, -INFINITY, -INFINITY, -INFINITY);

  if (k4 < 100) {
    const float* base = R + (size_t)b * CCH * IMG + (size_t)(i0 + irow) * NB + k4 * 4;
#pragma unroll 4
    for (int c = 0; c < CCH; ++c) {
      float4 v = *reinterpret_cast<const float4*>(base + (size_t)c * IMG);
      m.x = fmaxf(m.x, v.x);
      m.y = fmaxf(m.y, v.y);
      m.z = fmaxf(m.z, v.z);
      m.w = fmaxf(m.w, v.w);
    }
  }

  // tile[j][irow], stride 5 (gcd(5,32)=1 -> conflict-free column reads)
  __shared__ float tile[NB][5];
  if (k4 < 100) {
    tile[k4 * 4 + 0][irow] = fmaxf(tanhf(m.x), 0.0f);
    tile[k4 * 4 + 1][irow] = fmaxf(tanhf(m.y), 0.0f);
    tile[k4 * 4 + 2][irow] = fmaxf(tanhf(m.z), 0.0f);
    tile[k4 * 4 + 3][irow] = fmaxf(tanhf(m.w), 0.0f);
  }
  __syncthreads();

  if (tid < NB) {
    float4 v;
    v.x = tile[tid][0];
    v.y = tile[tid][1];
    v.z = tile[tid][2];
    v.w = tile[tid][3];
    // i0 is a multiple of 4 -> 16B-aligned float4 store
    *reinterpret_cast<float4*>(Tt + ((size_t)b * NB + tid) * NB + i0) = v;
  }
}

// ---------------------------------------------------------------------------
// K2: x[b][c][k] = sum_n R[b,c,n,k] * Tt[b][n][k]
// Block = (b,c), 1024 threads: slice = tid>>7 (8 n-slices of 50), k4 = tid&127
// (active < 100). Both streams coalesced along k; Tt hits L2/L3.
// Grid 512 blocks x 16 waves -> 8 waves/SIMD.
// ---------------------------------------------------------------------------
__global__ __launch_bounds__(1024) void k2_reduce_n(
    const float* __restrict__ R, const float* __restrict__ Tt,
    float* __restrict__ x) {
  const int c     = blockIdx.x;
  const int b     = blockIdx.y;
  const int tid   = threadIdx.x;
  const int slice = tid >> 7;            // 0..7
  const int k4    = tid & 127;           // active if < 100
  const int kk    = k4 * 4;

  const float* Rbc = R + ((size_t)b * CCH + c) * IMG + kk;
  const float* Ttb = Tt + (size_t)b * IMG + kk;

  float4 acc = make_float4(0.f, 0.f, 0.f, 0.f);
  if (k4 < 100) {
    const int n0 = slice * 50;
#pragma unroll 5
    for (int n = n0; n < n0 + 50; ++n) {
      float4 r = *reinterpret_cast<const float4*>(Rbc + (size_t)n * NB);
      float4 t = *reinterpret_cast<const float4*>(Ttb + (size_t)n * NB);
      acc.x += r.x * t.x;
      acc.y += r.y * t.y;
      acc.z += r.z * t.z;
      acc.w += r.w * t.w;
    }
  }

  __shared__ float4 red[8][100];
  if (slice != 0 && k4 < 100) red[slice][k4] = acc;
  __syncthreads();
  if (slice == 0 && k4 < 100) {
#pragma unroll
    for (int s = 1; s < 8; ++s) {
      float4 o = red[s][k4];
      acc.x += o.x; acc.y += o.y; acc.z += o.z; acc.w += o.w;
    }
    *reinterpret_cast<float4*>(x + ((size_t)b * CCH + c) * NB + kk) = acc;
  }
}

// ---------------------------------------------------------------------------
// K3: out[b][o][n] = bias[o] + sum_c W[o][c] * x[b][c][n]
// Block per (b, 64-wide n tile). W staged in LDS transposed to [c][o] so each
// LDS read is wave-uniform (broadcast). Each thread: 1 n, 16 o's.
// ---------------------------------------------------------------------------
__global__ __launch_bounds__(256) void k3_linear(
    const float* __restrict__ x, const float* __restrict__ W,
    const float* __restrict__ bias, float* __restrict__ out) {
  const int b  = blockIdx.y;
  const int n0 = blockIdx.x * 64;
  const int tid = threadIdx.x;
  const int nl = tid & 63;
  const int og = tid >> 6;       // wave id 0..3
  const int o0 = og * 16;
  const int n = n0 + nl;

  __shared__ float Ws[64][64];   // Ws[c][o] = W[o][c]
  for (int idx = tid; idx < 64 * 64; idx += 256) {
    const int o = idx >> 6, c = idx & 63;
    Ws[c][o] = W[idx];
  }
  __syncthreads();

  float acc[16];
#pragma unroll
  for (int t = 0; t < 16; ++t) acc[t] = bias[o0 + t];

  if (n < NB) {
    const float* xb = x + (size_t)b * CCH * NB;
    for (int cc = 0; cc < CCH; ++cc) {
      const float xv = xb[(size_t)cc * NB + n];
#pragma unroll
      for (int q = 0; q < 4; ++q) {
        float4 w = *reinterpret_cast<const float4*>(&Ws[cc][o0 + q * 4]);
        acc[q * 4 + 0] += w.x * xv;
        acc[q * 4 + 1] += w.y * xv;
        acc[q * 4 + 2] += w.z * xv;
        acc[q * 4 + 3] += w.w * xv;
      }
    }
#pragma unroll
    for (int t = 0; t < 16; ++t) {
      out[((size_t)b * CCH + (o0 + t)) * NB + n] = acc[t];
    }
  }
}

// ---------------------------------------------------------------------------
extern "C" void kernel_launch(void* const* d_in, const int* in_sizes, int n_in,
                              void* d_out, int out_size, void* d_ws, size_t ws_size,
                              hipStream_t stream) {
  const float* R    = (const float*)d_in[0];   // (8,64,400,400)
  const float* W    = (const float*)d_in[1];   // (64,64)
  const float* bias = (const float*)d_in[2];   // (64,)
  float* out = (float*)d_out;                  // (8,64,400,1)

  float* Tt = (float*)d_ws;                        // 8*400*400 floats
  float* x  = (float*)d_ws + (size_t)8 * IMG;      // 8*64*400 floats

  dim3 g1(NB / 4, 8);                          // 100 x 8 = 800 blocks
  k1_max_tanh_T<<<g1, 512, 0, stream>>>(R, Tt);

  dim3 g2(CCH, 8);                             // 64 x 8 = 512 blocks
  k2_reduce_n<<<g2, 1024, 0, stream>>>(R, Tt, x);

  dim3 g3((NB + 63) / 64, 8);                  // 7 x 8
  k3_linear<<<g3, 256, 0, stream>>>(x, W, bias, out);
}